// Round 2
// baseline (31.078 us; speedup 1.0000x reference)
//
#include <hip/hip_runtime.h>

#define HH 2048
#define WW 2048
#define CC 3
#define OH 512
#define OW 512
#define TKC 32         // output cols per block (threads x)
#define TKR 16         // output rows per block (8 ty threads x 2 rows each)
#define ROWS 70        // 4*TKR + 6 halo
#define PITCH 136      // 4*TKC + 8 ; 136 floats = 34 float4 per row (linear!)
#define V4_PER_ROW 34
#define NV4 (ROWS * V4_PER_ROW)   // 2380 float4 chunks per tile

__device__ __forceinline__ float rfl(float v) {
    return __int_as_float(__builtin_amdgcn_readfirstlane(__float_as_int(v)));
}

__global__ __launch_bounds__(256, 3)
void wpt2_kernel(const float* __restrict__ x,
                 const float* __restrict__ dec_lo,
                 const float* __restrict__ dec_hi,
                 float* __restrict__ out) {
    __shared__ float tile[NV4 * 4];   // 70 x 136 floats, linear in vec4 index

    const int tx  = threadIdx.x;              // 0..31 -> kc
    const int ty  = threadIdx.y;              // 0..7  -> output rows 2ty, 2ty+1
    const int tid = ty * TKC + tx;
    const int kc0 = blockIdx.x * TKC;
    const int kr0 = blockIdx.y * TKR;
    const int ch  = blockIdx.z;

    // ---------------- async stage input tile to LDS (global_load_lds x16B) ----
    // tile covers global rows [4*kr0-6, 4*kr0+63], cols [4*kc0-8, 4*kc0+127]
    const float* xc = x + (size_t)ch * HH * WW;
    const int r0 = 4 * kr0 - 6;
    const int c0 = 4 * kc0 - 8;
#pragma unroll
    for (int k = 0; k < 10; ++k) {
        const int i = k * 256 + tid;
        if (i < NV4) {
            const int rr = i / V4_PER_ROW;
            const int vc = i - rr * V4_PER_ROW;
            int gr = r0 + rr;      if (gr < 0) gr += HH;   // whole-row wrap only
            int gc = c0 + 4 * vc;  if (gc < 0) gc += WW;   // whole-vec4 wrap only
            const float* src = &xc[(size_t)gr * WW + gc];
            __builtin_amdgcn_global_load_lds(
                (const __attribute__((address_space(1))) void*)src,
                (__attribute__((address_space(3))) void*)&tile[i * 4],
                16, 0, 0);
        }
    }

    // ---------------- composed 10-tap filters -> SGPRs ----------------
    // GRAY[g] = (level1 band, level2 band): (0,0),(0,1),(1,1),(1,0)
    float lo[4], hi[4];
#pragma unroll
    for (int j = 0; j < 4; ++j) { lo[j] = dec_lo[j]; hi[j] = dec_hi[j]; }
    float F[4][10];
#pragma unroll
    for (int g = 0; g < 4; ++g) {
        const float* f1 = (g >= 2) ? hi : lo;             // level-1: 0,0,1,1
        const float* f2 = (g == 1 || g == 2) ? hi : lo;   // level-2: 0,1,1,0
#pragma unroll
        for (int d = 0; d < 10; ++d) F[g][d] = 0.f;
#pragma unroll
        for (int j2 = 0; j2 < 4; ++j2)
#pragma unroll
            for (int j1 = 0; j1 < 4; ++j1)
                F[g][2 * j2 + j1] = fmaf(f2[j2], f1[j1], F[g][2 * j2 + j1]);
    }
#pragma unroll
    for (int g = 0; g < 4; ++g)
#pragma unroll
        for (int d = 0; d < 10; ++d) F[g][d] = rfl(F[g][d]);  // -> SGPR file

    __syncthreads();

    // ---------------- row pass: two output rows per thread, shared window ----
    // output kr = kr0 + 2*ty + p ; input row 4kr+3-dr -> local lr = 8ty+4p+9-dr
    // u = lr - 8ty in [0,13]; p=0: dr=9-u (u<=9); p=1: dr=13-u (u>=4)
    float t0[4][10], t1[4][10];
#pragma unroll
    for (int g = 0; g < 4; ++g)
#pragma unroll
        for (int d = 0; d < 10; ++d) { t0[g][d] = 0.f; t1[g][d] = 0.f; }

#pragma unroll
    for (int u = 0; u < 14; ++u) {
        const float* rp = &tile[(8 * ty + u) * PITCH + 4 * tx];
        const float4 a = *reinterpret_cast<const float4*>(rp);
        const float4 b = *reinterpret_cast<const float4*>(rp + 4);
        const float4 c = *reinterpret_cast<const float4*>(rp + 8);
        const float row[12] = {a.x, a.y, a.z, a.w, b.x, b.y, b.z, b.w,
                               c.x, c.y, c.z, c.w};
        if (u <= 9) {
            const int dr = 9 - u;
#pragma unroll
            for (int dc = 0; dc < 10; ++dc) {
                const float v = row[11 - dc];
#pragma unroll
                for (int g = 0; g < 4; ++g)
                    t0[g][dc] = fmaf(F[g][dr], v, t0[g][dc]);
            }
        }
        if (u >= 4) {
            const int dr = 13 - u;
#pragma unroll
            for (int dc = 0; dc < 10; ++dc) {
                const float v = row[11 - dc];
#pragma unroll
                for (int g = 0; g < 4; ++g)
                    t1[g][dc] = fmaf(F[g][dr], v, t1[g][dc]);
            }
        }
    }

    // ---------------- column combine + store 16 bands x 2 rows ----------------
    const int kc = kc0 + tx;
    const int krA = kr0 + 2 * ty;
#pragma unroll
    for (int gi = 0; gi < 4; ++gi) {
#pragma unroll
        for (int gj = 0; gj < 4; ++gj) {
            float accA = 0.f, accB = 0.f;
#pragma unroll
            for (int dc = 0; dc < 10; ++dc) {
                accA = fmaf(F[gj][dc], t0[gi][dc], accA);
                accB = fmaf(F[gj][dc], t1[gi][dc], accB);
            }
            const size_t band = (size_t)(ch * 16 + gi * 4 + gj);
            out[(band * OH + krA) * OW + kc]     = accA;
            out[(band * OH + krA + 1) * OW + kc] = accB;
        }
    }
}

extern "C" void kernel_launch(void* const* d_in, const int* in_sizes, int n_in,
                              void* d_out, int out_size, void* d_ws, size_t ws_size,
                              hipStream_t stream) {
    const float* x      = (const float*)d_in[0];
    const float* dec_lo = (const float*)d_in[1];
    const float* dec_hi = (const float*)d_in[2];
    float* out          = (float*)d_out;

    dim3 grid(OW / TKC, OH / TKR, CC);   // 16 x 32 x 3
    dim3 block(TKC, 8);                  // 32 x 8 = 256
    hipLaunchKernelGGL(wpt2_kernel, grid, block, 0, stream, x, dec_lo, dec_hi, out);
}

// Round 3
// 26.674 us; speedup vs baseline: 1.1651x; 1.1651x over previous
//
#include <hip/hip_runtime.h>

#define HH 2048
#define WW 2048
#define CC 3
#define OH 512
#define OW 512
#define TKC 32             // output cols per tile (= threads x)
#define TKR 8              // output rows per tile (= threads y)
#define ROWS 38            // 4*TKR + 6 halo rows
#define PITCHF 144         // 16-float lead pad + 128; rows are 576 B = 9 aligned lines
#define V4PR 36            // PITCHF/4
#define NV4 (ROWS * V4PR)  // 1368 float4 per tile (21.9 KB); two buffers = 43.8 KB
#define NBLK 768           // blocks; 3 per CU (LDS-limited)
#define TPB 4              // tiles per block; 768*4 = 3072 = 3ch * 64 * 16
#define CTILES 16
#define PERCH 1024         // 64*16 tiles per channel

__device__ __forceinline__ float rfl(float v) {
    return __int_as_float(__builtin_amdgcn_readfirstlane(__float_as_int(v)));
}

__global__ __launch_bounds__(256, 3)
void wpt2_kernel(const float* __restrict__ x,
                 const float* __restrict__ dec_lo,
                 const float* __restrict__ dec_hi,
                 float* __restrict__ out) {
    __shared__ float bufA[NV4 * 4];
    __shared__ float bufB[NV4 * 4];

    const int tx  = threadIdx.x;          // 0..31
    const int ty  = threadIdx.y;          // 0..7
    const int tid = ty * TKC + tx;

    // bijective XCD swizzle (768 % 8 == 0): 96 consecutive work-chunks per XCD
    const int bid = blockIdx.x;
    const int swz = (bid & 7) * (NBLK / 8) + (bid >> 3);
    const int tile0 = swz * TPB;          // 4 consecutive tiles (adjacent col-tiles)

    // ---- composed 10-tap filters (graycode order), pinned to SGPRs ----
    float lo[4], hi[4];
#pragma unroll
    for (int j = 0; j < 4; ++j) { lo[j] = dec_lo[j]; hi[j] = dec_hi[j]; }
    float F[4][10];
#pragma unroll
    for (int g = 0; g < 4; ++g) {
        const float* f1 = (g >= 2) ? hi : lo;             // level-1: 0,0,1,1
        const float* f2 = (g == 1 || g == 2) ? hi : lo;   // level-2: 0,1,1,0
#pragma unroll
        for (int d = 0; d < 10; ++d) F[g][d] = 0.f;
#pragma unroll
        for (int j2 = 0; j2 < 4; ++j2)
#pragma unroll
            for (int j1 = 0; j1 < 4; ++j1)
                F[g][2 * j2 + j1] = fmaf(f2[j2], f1[j1], F[g][2 * j2 + j1]);
    }
#pragma unroll
    for (int g = 0; g < 4; ++g)
#pragma unroll
        for (int d = 0; d < 10; ++d) F[g][d] = rfl(F[g][d]);

    // ---- async stage one tile into an LDS buffer (linear, global_load_lds x16B) ----
    auto stage = [&](float* dst, int tileId) {
        const int ch  = tileId >> 10;             // / PERCH
        const int rem = tileId & (PERCH - 1);
        const int trr = rem >> 4;                 // / CTILES
        const int tcc = rem & (CTILES - 1);
        const float* xc = x + (size_t)ch * HH * WW;
        const int r0 = 32 * trr - 6;
        const int c0 = 128 * tcc - 16;
#pragma unroll
        for (int j = 0; j < 6; ++j) {
            const int i = j * 256 + tid;
            if (j < 5 || i < NV4) {
                const int rr = i / V4PR;
                const int vc = i - rr * V4PR;
                int gr = r0 + rr;      if (gr < 0) gr += HH;   // whole-row wrap only
                int gc = c0 + 4 * vc;  if (gc < 0) gc += WW;   // whole-vec4 wrap only
                __builtin_amdgcn_global_load_lds(
                    (const __attribute__((address_space(1))) void*)&xc[(size_t)gr * WW + gc],
                    (__attribute__((address_space(3))) void*)&dst[i * 4],
                    16, 0, 0);
            }
        }
    };

    // ---- compute one tile from an LDS buffer ----
    auto compute = [&](const float* buf, int tileId) {
        const int ch  = tileId >> 10;
        const int rem = tileId & (PERCH - 1);
        const int trr = rem >> 4;
        const int tcc = rem & (CTILES - 1);

        float t[4][10];
#pragma unroll
        for (int g = 0; g < 4; ++g)
#pragma unroll
            for (int d = 0; d < 10; ++d) t[g][d] = 0.f;

        // local row u = 4*ty + (9 - dr); local col for dc = 4*tx + 19 - dc
#pragma unroll
        for (int u = 0; u < 10; ++u) {
            const float* rp = &buf[(4 * ty + u) * PITCHF + 4 * tx + 8];
            const float4 a = *reinterpret_cast<const float4*>(rp);
            const float4 b = *reinterpret_cast<const float4*>(rp + 4);
            const float4 c = *reinterpret_cast<const float4*>(rp + 8);
            const float row[12] = {a.x, a.y, a.z, a.w, b.x, b.y, b.z, b.w,
                                   c.x, c.y, c.z, c.w};
            const int dr = 9 - u;
#pragma unroll
            for (int dc = 0; dc < 10; ++dc) {
                const float v = row[11 - dc];
#pragma unroll
                for (int g = 0; g < 4; ++g)
                    t[g][dc] = fmaf(F[g][dr], v, t[g][dc]);
            }
        }

        const int kr = TKR * trr + ty;
        const int kc = TKC * tcc + tx;
        const size_t plane = (size_t)OH * OW;
        const size_t obase = (size_t)(ch * 16) * plane + (size_t)kr * OW + kc;
#pragma unroll
        for (int gi = 0; gi < 4; ++gi) {
#pragma unroll
            for (int gj = 0; gj < 4; ++gj) {
                float acc = 0.f;
#pragma unroll
                for (int dc = 0; dc < 10; ++dc)
                    acc = fmaf(F[gj][dc], t[gi][dc], acc);
                out[obase + (size_t)(gi * 4 + gj) * plane] = acc;
            }
        }
    };

    // ---- 2-phase double-buffered pipeline over 4 tiles (static buffers) ----
    stage(bufA, tile0);
    __syncthreads();
    stage(bufB, tile0 + 1); compute(bufA, tile0);     __syncthreads();
    stage(bufA, tile0 + 2); compute(bufB, tile0 + 1); __syncthreads();
    stage(bufB, tile0 + 3); compute(bufA, tile0 + 2); __syncthreads();
    compute(bufB, tile0 + 3);
}

extern "C" void kernel_launch(void* const* d_in, const int* in_sizes, int n_in,
                              void* d_out, int out_size, void* d_ws, size_t ws_size,
                              hipStream_t stream) {
    const float* x      = (const float*)d_in[0];
    const float* dec_lo = (const float*)d_in[1];
    const float* dec_hi = (const float*)d_in[2];
    float* out          = (float*)d_out;

    hipLaunchKernelGGL(wpt2_kernel, dim3(NBLK), dim3(TKC, TKR), 0, stream,
                       x, dec_lo, dec_hi, out);
}